// Round 3
// baseline (28.323 us; speedup 1.0000x reference)
//
#include <hip/hip_runtime.h>
#include <hip/hip_bf16.h>

typedef __attribute__((ext_vector_type(8))) short short8_t;
typedef __attribute__((ext_vector_type(4))) short short4_t;
typedef __attribute__((ext_vector_type(4))) float f32x4;

#define S_DIM   1024
#define D_DIM   64
#define BM      64             // rows per block (R3: halved -> 512 blocks, 2/CU)
#define KC      64
#define NCHUNK  (S_DIM / KC)   // 16
#define BSTRIDE 72             // u16 per row of B^T chunk (144B, 16B-aligned, bank-spread)
#define THREADS 512

__device__ __forceinline__ ushort f2bf(float f) {
    __hip_bfloat16 h = __float2bfloat16(f);   // RTNE
    return __builtin_bit_cast(ushort, h);
}

// Raw-barrier publish: waits only LDS ops, leaves global loads IN FLIGHT
// across the barrier (no vmcnt(0) drain).
#define SYNC() do { \
    __builtin_amdgcn_sched_barrier(0); \
    asm volatile("s_waitcnt lgkmcnt(0)"); \
    __builtin_amdgcn_s_barrier(); \
    __builtin_amdgcn_sched_barrier(0); \
} while (0)

__global__ __launch_bounds__(THREADS, 4)   // 4 waves/SIMD -> VGPR<=128 -> 2 blocks/CU
void gemm_sm_kernel(const float* __restrict__ x1,
                    const float* __restrict__ x2,
                    float* __restrict__ out) {
    // double-buffered: A [64 rows][64 k] bf16 XOR-swizzled (8KB), B^T [64 d][72] (9KB)
    __shared__ ushort lds_a[2][BM * KC];
    __shared__ ushort lds_b[2][D_DIM * BSTRIDE];

    const int tid = threadIdx.x;
    const int bid = blockIdx.x;
    // XCD-aware: bid&7 = XCD; each XCD owns 4 batches (B panels 1MB -> L2-resident)
    const int xcd = bid & 7;
    const int q   = bid >> 3;              // 0..63
    const int batch   = xcd * 4 + (q & 3); // 0..31
    const int rowtile = q >> 2;            // 0..15
    const int row0    = rowtile * BM;

    const float* Abase = x1 + (size_t)batch * (S_DIM * S_DIM) + (size_t)row0 * S_DIM;
    const float* Bbase = x2 + (size_t)batch * (S_DIM * D_DIM);
    float*       Cbase = out + (size_t)batch * (S_DIM * D_DIM) + (size_t)row0 * D_DIM;

    const int w = tid >> 6;   // wave 0..7
    const int l = tid & 63;   // lane

    // ---- A staging: thread covers 8 floats (one short8 slot) of one row ----
    const int ar  = tid >> 3;              // row 0..63
    const int ak8 = (tid & 7) * 8;         // k-offset 0..56
    const float* aptr = Abase + (size_t)ar * S_DIM + ak8;
    const int aw = (ar * KC + ak8) ^ ((ar & 7) << 3);   // u16 units, 16B-aligned

    // ---- B staging: lane = d, wave picks k-groups ----
    const int bd  = l;
    const int bk0 = w * 4;                 // k-local base (+32 for second half)

    // ---- fragment indices: wave tile 16 rows x 32 cols (wm 0..3, wn 0..1) ----
    const int wm = w >> 1, wn = w & 1;
    const int fr = l & 15, fg = l >> 4;
    int aidx[2], bidx[2][2];
    {
        const int row = wm * 16 + fr;
        #pragma unroll
        for (int ks = 0; ks < 2; ++ks)
            aidx[ks] = (row * KC + ks * 32 + fg * 8) ^ ((row & 7) << 3);
    }
    #pragma unroll
    for (int nf = 0; nf < 2; ++nf) {
        const int col = wn * 32 + nf * 16 + fr;
        #pragma unroll
        for (int ks = 0; ks < 2; ++ks)
            bidx[nf][ks] = col * BSTRIDE + ks * 32 + fg * 8;
    }

    // 2-deep register prefetch (named buffers -> static indexing)
    float a0[8], a1[8], b0[8], b1[8];

    auto load_chunk = [&](int t, float (&A)[8], float (&B)[8]) {
        const float* p = aptr + t * KC;
        #pragma unroll
        for (int i = 0; i < 2; ++i) {
            float4 v = *reinterpret_cast<const float4*>(p + i * 4);
            A[i * 4 + 0] = v.x; A[i * 4 + 1] = v.y;
            A[i * 4 + 2] = v.z; A[i * 4 + 3] = v.w;
        }
        const float* bp = Bbase + (size_t)t * KC * D_DIM + bd;
        #pragma unroll
        for (int i = 0; i < 2; ++i)
            #pragma unroll
            for (int j = 0; j < 4; ++j)
                B[i * 4 + j] = bp[(bk0 + 32 * i + j) * D_DIM];
    };

    auto store_chunk = [&](ushort* la, ushort* lb,
                           const float (&A)[8], const float (&B)[8]) {
        short8_t v0;
        #pragma unroll
        for (int j = 0; j < 8; ++j) v0[j] = (short)f2bf(A[j]);
        *reinterpret_cast<short8_t*>(&la[aw]) = v0;
        #pragma unroll
        for (int i = 0; i < 2; ++i) {
            short4_t bv;
            #pragma unroll
            for (int j = 0; j < 4; ++j) bv[j] = (short)f2bf(B[i * 4 + j]);
            *reinterpret_cast<short4_t*>(&lb[bd * BSTRIDE + bk0 + 32 * i]) = bv;
        }
    };

    f32x4 acc[2];
    acc[0] = f32x4{0.f, 0.f, 0.f, 0.f};
    acc[1] = f32x4{0.f, 0.f, 0.f, 0.f};

    auto compute = [&](const ushort* la, const ushort* lb) {
        short8_t af[2], bf[2][2];
        #pragma unroll
        for (int ks = 0; ks < 2; ++ks)
            af[ks] = *reinterpret_cast<const short8_t*>(&la[aidx[ks]]);
        #pragma unroll
        for (int nf = 0; nf < 2; ++nf)
            #pragma unroll
            for (int ks = 0; ks < 2; ++ks)
                bf[nf][ks] = *reinterpret_cast<const short8_t*>(&lb[bidx[nf][ks]]);
        #pragma unroll
        for (int ks = 0; ks < 2; ++ks)
            #pragma unroll
            for (int nf = 0; nf < 2; ++nf)
                acc[nf] = __builtin_amdgcn_mfma_f32_16x16x32_bf16(
                    af[ks], bf[nf][ks], acc[nf], 0, 0, 0);
    };

    // ---- pipeline: chunk t in regs (t&1 ? a1 : a0); LDS buf = t&1 ----
    load_chunk(0, a0, b0);
    load_chunk(1, a1, b1);
    store_chunk(&lds_a[0][0], &lds_b[0][0], a0, b0);
    SYNC();

    #pragma unroll 1
    for (int ti = 0; ti < NCHUNK; ti += 2) {
        if (ti + 2 < NCHUNK) load_chunk(ti + 2, a0, b0);
        store_chunk(&lds_a[1][0], &lds_b[1][0], a1, b1);
        compute(&lds_a[0][0], &lds_b[0][0]);
        SYNC();

        if (ti + 3 < NCHUNK) load_chunk(ti + 3, a1, b1);
        if (ti + 2 < NCHUNK) store_chunk(&lds_a[0][0], &lds_b[0][0], a0, b0);
        compute(&lds_a[1][0], &lds_b[1][0]);
        SYNC();
    }

    // epilogue: C/D layout col = lane&15, row = (lane>>4)*4 + j  [m89-verified]
    #pragma unroll
    for (int nf = 0; nf < 2; ++nf)
        #pragma unroll
        for (int j = 0; j < 4; ++j) {
            const int r = wm * 16 + fg * 4 + j;
            const int c = wn * 32 + nf * 16 + fr;
            Cbase[(size_t)r * D_DIM + c] = acc[nf][j];
        }
}

extern "C" void kernel_launch(void* const* d_in, const int* in_sizes, int n_in,
                              void* d_out, int out_size, void* d_ws, size_t ws_size,
                              hipStream_t stream) {
    const float* x1 = (const float*)d_in[0];
    const float* x2 = (const float*)d_in[1];
    float* out = (float*)d_out;
    dim3 grid(512), block(THREADS);
    gemm_sm_kernel<<<grid, block, 0, stream>>>(x1, x2, out);
}